// Round 1
// baseline (408.778 us; speedup 1.0000x reference)
//
#include <hip/hip_runtime.h>
#include <stdint.h>
#include <math.h>

#define B_ 32
#define S_ 512
#define H_ 768
#define V_ 30522
#define M_ (B_*S_)   // 16384
#define N1_ 512
#define NA_ 100

__device__ __forceinline__ float bf2f(unsigned short u){
  union { unsigned int u; float f; } c; c.u = ((unsigned int)u)<<16; return c.f;
}
__device__ __forceinline__ unsigned short f2bf(float f){
  union { float f; unsigned int u; } c; c.f=f;
  unsigned int u = c.u + 0x7FFFu + ((c.u>>16)&1u);
  return (unsigned short)(u>>16);
}
__device__ __forceinline__ bool tbl_get(const void* t, int id, int flag){
  if(flag==1) return ((const int*)t)[id]!=0;
  if(flag==2) return ((const unsigned int*)t)[id]!=0u;   // f32 stored 0.0/1.0
  return ((const unsigned char*)t)[id]!=0;
}

// ---- K0: detect in_table storage layout (u8 bool vs int32 vs f32) ----
__global__ void k_detect(const void* __restrict__ in_table, int* __restrict__ flag){
  if(threadIdx.x==0 && blockIdx.x==0){
    const int* pi = (const int*)in_table;
    bool all01=true, allf=true;
    for(int i=0;i<64;i++){
      int v = pi[i];
      if(v!=0 && v!=1) all01=false;
      unsigned int u=(unsigned int)v;
      if(u!=0u && u!=0x3F800000u) allf=false;
    }
    *flag = all01 ? 1 : (allf ? 2 : 0);
  }
}

// ---- K1: x = relu(table[ids] @ W1^T + b1), store bf16.  M=16384,N=512,K=768
__global__ __launch_bounds__(256) void k_mlp1(
  const float* __restrict__ table, const int* __restrict__ ids,
  const float* __restrict__ W1, const float* __restrict__ b1,
  unsigned short* __restrict__ xo)
{
  __shared__ __align__(16) float As[32][68];
  __shared__ __align__(16) float Bs[32][68];
  __shared__ int ids_s[64];
  const int tid = threadIdx.x;
  const int m0 = (blockIdx.x >> 3) << 6;
  const int n0 = (blockIdx.x & 7) << 6;
  if(tid < 64) ids_s[tid] = ids[m0 + tid];
  __syncthreads();
  const int tm = tid & 15, tn = tid >> 4;
  const int lr = tid >> 2, lc = (tid & 3) << 3;
  const size_t arow = (size_t)ids_s[lr] * H_;
  const size_t brow = (size_t)(n0 + lr) * H_;
  float acc[4][4] = {{0.f,0.f,0.f,0.f},{0.f,0.f,0.f,0.f},{0.f,0.f,0.f,0.f},{0.f,0.f,0.f,0.f}};
  for(int k0=0; k0<H_; k0+=32){
    const float4 a0 = *(const float4*)(table + arow + k0 + lc);
    const float4 a1 = *(const float4*)(table + arow + k0 + lc + 4);
    const float4 b0 = *(const float4*)(W1 + brow + k0 + lc);
    const float4 b1v= *(const float4*)(W1 + brow + k0 + lc + 4);
    __syncthreads();
    As[lc+0][lr]=a0.x; As[lc+1][lr]=a0.y; As[lc+2][lr]=a0.z; As[lc+3][lr]=a0.w;
    As[lc+4][lr]=a1.x; As[lc+5][lr]=a1.y; As[lc+6][lr]=a1.z; As[lc+7][lr]=a1.w;
    Bs[lc+0][lr]=b0.x; Bs[lc+1][lr]=b0.y; Bs[lc+2][lr]=b0.z; Bs[lc+3][lr]=b0.w;
    Bs[lc+4][lr]=b1v.x; Bs[lc+5][lr]=b1v.y; Bs[lc+6][lr]=b1v.z; Bs[lc+7][lr]=b1v.w;
    __syncthreads();
    #pragma unroll
    for(int kk=0;kk<32;kk++){
      const float4 av = *(const float4*)(&As[kk][tm<<2]);
      const float4 bv = *(const float4*)(&Bs[kk][tn<<2]);
      const float aa[4]={av.x,av.y,av.z,av.w};
      const float bb[4]={bv.x,bv.y,bv.z,bv.w};
      #pragma unroll
      for(int i=0;i<4;i++)
        #pragma unroll
        for(int j=0;j<4;j++)
          acc[i][j] = fmaf(aa[i], bb[j], acc[i][j]);
    }
  }
  #pragma unroll
  for(int i=0;i<4;i++){
    const int m = m0 + (tm<<2) + i;
    ushort4 sv;
    float v0 = fmaxf(acc[i][0] + b1[n0+(tn<<2)+0], 0.f);
    float v1 = fmaxf(acc[i][1] + b1[n0+(tn<<2)+1], 0.f);
    float v2 = fmaxf(acc[i][2] + b1[n0+(tn<<2)+2], 0.f);
    float v3 = fmaxf(acc[i][3] + b1[n0+(tn<<2)+3], 0.f);
    sv.x=f2bf(v0); sv.y=f2bf(v1); sv.z=f2bf(v2); sv.w=f2bf(v3);
    *(ushort4*)(xo + (size_t)m*N1_ + n0 + (tn<<2)) = sv;
  }
}

// ---- K2: wh = mask * relu(x @ W2^T + b2), store bf16.  M=16384,N=768,K=512
__global__ __launch_bounds__(256) void k_mlp2(
  const unsigned short* __restrict__ x, const float* __restrict__ W2, const float* __restrict__ b2,
  const int* __restrict__ ids, const void* __restrict__ in_table, const int* __restrict__ flagp,
  unsigned short* __restrict__ who)
{
  __shared__ __align__(16) float As[32][68];
  __shared__ __align__(16) float Bs[32][68];
  __shared__ int ids_s[64];
  const int tid = threadIdx.x;
  const int m0 = (blockIdx.x / 12) << 6;
  const int n0 = (blockIdx.x % 12) << 6;
  if(tid < 64) ids_s[tid] = ids[m0 + tid];
  __syncthreads();
  const int tm = tid & 15, tn = tid >> 4;
  const int lr = tid >> 2, lc = (tid & 3) << 3;
  const size_t arow = (size_t)(m0 + lr) * N1_;
  const size_t brow = (size_t)(n0 + lr) * N1_;
  float acc[4][4] = {{0.f,0.f,0.f,0.f},{0.f,0.f,0.f,0.f},{0.f,0.f,0.f,0.f},{0.f,0.f,0.f,0.f}};
  for(int k0=0; k0<N1_; k0+=32){
    const uint4 a = *(const uint4*)(x + arow + k0 + lc);
    const float4 b0 = *(const float4*)(W2 + brow + k0 + lc);
    const float4 b1v= *(const float4*)(W2 + brow + k0 + lc + 4);
    __syncthreads();
    As[lc+0][lr]=bf2f((unsigned short)(a.x&0xffffu)); As[lc+1][lr]=bf2f((unsigned short)(a.x>>16));
    As[lc+2][lr]=bf2f((unsigned short)(a.y&0xffffu)); As[lc+3][lr]=bf2f((unsigned short)(a.y>>16));
    As[lc+4][lr]=bf2f((unsigned short)(a.z&0xffffu)); As[lc+5][lr]=bf2f((unsigned short)(a.z>>16));
    As[lc+6][lr]=bf2f((unsigned short)(a.w&0xffffu)); As[lc+7][lr]=bf2f((unsigned short)(a.w>>16));
    Bs[lc+0][lr]=b0.x; Bs[lc+1][lr]=b0.y; Bs[lc+2][lr]=b0.z; Bs[lc+3][lr]=b0.w;
    Bs[lc+4][lr]=b1v.x; Bs[lc+5][lr]=b1v.y; Bs[lc+6][lr]=b1v.z; Bs[lc+7][lr]=b1v.w;
    __syncthreads();
    #pragma unroll
    for(int kk=0;kk<32;kk++){
      const float4 av = *(const float4*)(&As[kk][tm<<2]);
      const float4 bv = *(const float4*)(&Bs[kk][tn<<2]);
      const float aa[4]={av.x,av.y,av.z,av.w};
      const float bb[4]={bv.x,bv.y,bv.z,bv.w};
      #pragma unroll
      for(int i=0;i<4;i++)
        #pragma unroll
        for(int j=0;j<4;j++)
          acc[i][j] = fmaf(aa[i], bb[j], acc[i][j]);
    }
  }
  const int flag = *flagp;
  #pragma unroll
  for(int i=0;i<4;i++){
    const int mloc = (tm<<2) + i;
    const int m = m0 + mloc;
    const int s = m & (S_-1);
    const bool mk = (s>0) && tbl_get(in_table, ids_s[mloc], flag);
    ushort4 sv;
    float v0 = mk ? fmaxf(acc[i][0] + b2[n0+(tn<<2)+0], 0.f) : 0.f;
    float v1 = mk ? fmaxf(acc[i][1] + b2[n0+(tn<<2)+1], 0.f) : 0.f;
    float v2 = mk ? fmaxf(acc[i][2] + b2[n0+(tn<<2)+2], 0.f) : 0.f;
    float v3 = mk ? fmaxf(acc[i][3] + b2[n0+(tn<<2)+3], 0.f) : 0.f;
    sv.x=f2bf(v0); sv.y=f2bf(v1); sv.z=f2bf(v2); sv.w=f2bf(v3);
    *(ushort4*)(who + (size_t)m*H_ + n0 + (tn<<2)) = sv;
  }
}

// ---- K3: scores[m] = Wa2 . tanh(wh[m] @ Wa1^T + ba1) + ba2.  32 rows/block, N padded 100->128
__global__ __launch_bounds__(256) void k_score(
  const unsigned short* __restrict__ wh, const float* __restrict__ Wa1,
  const float* __restrict__ ba1, const float* __restrict__ Wa2, const float* __restrict__ ba2,
  float* __restrict__ scores)
{
  __shared__ __align__(16) float As[32][36];
  __shared__ __align__(16) float Bs[32][132];
  __shared__ float sums[32][33];
  const int tid = threadIdx.x;
  const int m0 = blockIdx.x << 5;
  const int tm = tid & 7, tn = tid >> 3;
  const int ar = tid >> 3, ac = (tid & 7) << 2;   // A: 32 rows x 32 k, 4 bf16/thread
  const int br = tid >> 1, bc = (tid & 1) << 4;   // B: 128 rows x 32 k, 16 f32/thread
  float acc[4][4] = {{0.f,0.f,0.f,0.f},{0.f,0.f,0.f,0.f},{0.f,0.f,0.f,0.f},{0.f,0.f,0.f,0.f}};
  for(int k0=0; k0<H_; k0+=32){
    const ushort4 a = *(const ushort4*)(wh + (size_t)(m0+ar)*H_ + k0 + ac);
    float bv[16];
    if(br < NA_){
      const float* bp = Wa1 + (size_t)br*H_ + k0 + bc;
      #pragma unroll
      for(int q=0;q<4;q++){
        const float4 t = *(const float4*)(bp + (q<<2));
        bv[q*4+0]=t.x; bv[q*4+1]=t.y; bv[q*4+2]=t.z; bv[q*4+3]=t.w;
      }
    } else {
      #pragma unroll
      for(int q=0;q<16;q++) bv[q]=0.f;
    }
    __syncthreads();
    As[ac+0][ar]=bf2f(a.x); As[ac+1][ar]=bf2f(a.y); As[ac+2][ar]=bf2f(a.z); As[ac+3][ar]=bf2f(a.w);
    #pragma unroll
    for(int q=0;q<16;q++) Bs[bc+q][br]=bv[q];
    __syncthreads();
    #pragma unroll
    for(int kk=0;kk<32;kk++){
      const float4 av = *(const float4*)(&As[kk][tm<<2]);
      const float4 bb4 = *(const float4*)(&Bs[kk][tn<<2]);
      const float aa[4]={av.x,av.y,av.z,av.w};
      const float bb[4]={bb4.x,bb4.y,bb4.z,bb4.w};
      #pragma unroll
      for(int i=0;i<4;i++)
        #pragma unroll
        for(int j=0;j<4;j++)
          acc[i][j] = fmaf(aa[i], bb[j], acc[i][j]);
    }
  }
  #pragma unroll
  for(int i=0;i<4;i++){
    float p = 0.f;
    #pragma unroll
    for(int j=0;j<4;j++){
      const int n = (tn<<2) + j;
      if(n < NA_){
        const float t = tanhf(acc[i][j] + ba1[n]);
        p = fmaf(t, Wa2[n], p);
      }
    }
    sums[(tm<<2)+i][tn] = p;
  }
  __syncthreads();
  if(tid < 32){
    float s = ba2[0];
    for(int t=0;t<32;t++) s += sums[tid][t];
    scores[m0 + tid] = s;
  }
}

// ---- K4a: per-batch softmax over s=1..511 ----
__global__ __launch_bounds__(256) void k_softmax(const float* __restrict__ scores, float* __restrict__ attn){
  __shared__ float red[256];
  const int b = blockIdx.x, tid = threadIdx.x;
  const float s1 = (tid==0) ? -1e30f : scores[b*S_ + tid];
  const float s2 = scores[b*S_ + tid + 256];
  red[tid] = fmaxf(s1, s2); __syncthreads();
  for(int st=128; st>0; st>>=1){ if(tid<st) red[tid]=fmaxf(red[tid], red[tid+st]); __syncthreads(); }
  const float mx = red[0]; __syncthreads();
  const float e1 = (tid==0) ? 0.f : __expf(s1-mx);
  const float e2 = __expf(s2-mx);
  red[tid] = e1+e2; __syncthreads();
  for(int st=128; st>0; st>>=1){ if(tid<st) red[tid]+=red[tid+st]; __syncthreads(); }
  const float inv = 1.f/red[0];
  attn[b*S_+tid] = e1*inv;
  attn[b*S_+tid+256] = e2*inv;
}

// ---- K4b: partial[b][ch][h] = sum_{s in chunk} attn[s]*wh[b,s,h] ----
__global__ __launch_bounds__(256) void k_partial(const unsigned short* __restrict__ wh,
  const float* __restrict__ attn, float* __restrict__ partial){
  const int b = blockIdx.x >> 3, ch = blockIdx.x & 7, tid = threadIdx.x;
  __shared__ float wts[64];
  if(tid < 64) wts[tid] = attn[b*S_ + (ch<<6) + tid];
  __syncthreads();
  float a0=0.f, a1=0.f, a2=0.f;
  for(int t=0;t<64;t++){
    const float wv = wts[t];
    const size_t base = ((size_t)(b*S_ + (ch<<6) + t))*H_;
    a0 = fmaf(wv, bf2f(wh[base + tid      ]), a0);
    a1 = fmaf(wv, bf2f(wh[base + tid + 256]), a1);
    a2 = fmaf(wv, bf2f(wh[base + tid + 512]), a2);
  }
  float* pp = partial + ((size_t)((b<<3)+ch))*H_;
  pp[tid] = a0; pp[tid+256] = a1; pp[tid+512] = a2;
}

// ---- K5: predicts[b] = [hiddens[b,0,:], cls_k[b,:]] @ Wl^T + bl ----
__global__ __launch_bounds__(256) void k_predict(const float* __restrict__ hiddens,
  const float* __restrict__ partial, const float* __restrict__ Wl, const float* __restrict__ bl,
  float* __restrict__ out){
  __shared__ float ck[768];
  __shared__ float red[256];
  const int b = blockIdx.x, tid = threadIdx.x;
  #pragma unroll
  for(int r=0;r<3;r++){
    const int h = tid + (r<<8);
    float s=0.f;
    for(int c=0;c<8;c++) s += partial[((size_t)((b<<3)+c))*H_ + h];
    ck[h]=s;
  }
  __syncthreads();
  const float* hid = hiddens + (size_t)b * S_ * H_;
  for(int c=0;c<3;c++){
    float p=0.f;
    #pragma unroll
    for(int r=0;r<3;r++){
      const int h = tid + (r<<8);
      p = fmaf(hid[h], Wl[c*1536 + h], p);
      p = fmaf(ck[h],  Wl[c*1536 + 768 + h], p);
    }
    red[tid]=p; __syncthreads();
    for(int st=128; st>0; st>>=1){ if(tid<st) red[tid]+=red[tid+st]; __syncthreads(); }
    if(tid==0) out[b*3+c] = red[0] + bl[c];
    __syncthreads();
  }
}

extern "C" void kernel_launch(void* const* d_in, const int* in_sizes, int n_in,
                              void* d_out, int out_size, void* d_ws, size_t ws_size,
                              hipStream_t stream)
{
  const float* hiddens = (const float*)d_in[0];
  const int*   ids     = (const int*)d_in[1];
  const void*  in_tab  = d_in[2];
  const float* table   = (const float*)d_in[3];
  const float* W1      = (const float*)d_in[4];
  const float* b1      = (const float*)d_in[5];
  const float* W2      = (const float*)d_in[6];
  const float* b2      = (const float*)d_in[7];
  const float* Wa1     = (const float*)d_in[8];
  const float* ba1     = (const float*)d_in[9];
  const float* Wa2     = (const float*)d_in[10];
  const float* ba2     = (const float*)d_in[11];
  const float* Wl      = (const float*)d_in[12];
  const float* bl      = (const float*)d_in[13];
  float* out = (float*)d_out;

  char* w = (char*)d_ws;
  unsigned short* x  = (unsigned short*)w;                                // 16 MB
  unsigned short* wh = (unsigned short*)(w + (size_t)16*1024*1024);       // 24 MB
  float* scores  = (float*)(w + (size_t)42*1024*1024);                    // 64 KB
  float* attn    = scores + M_;                                           // 64 KB
  float* partial = attn + M_;                                             // 768 KB
  int*   flag    = (int*)(partial + 32*8*H_);

  hipLaunchKernelGGL(k_detect,  dim3(1),    dim3(64),  0, stream, in_tab, flag);
  hipLaunchKernelGGL(k_mlp1,    dim3(2048), dim3(256), 0, stream, table, ids, W1, b1, x);
  hipLaunchKernelGGL(k_mlp2,    dim3(3072), dim3(256), 0, stream, x, W2, b2, ids, in_tab, flag, wh);
  hipLaunchKernelGGL(k_score,   dim3(512),  dim3(256), 0, stream, wh, Wa1, ba1, Wa2, ba2, scores);
  hipLaunchKernelGGL(k_softmax, dim3(32),   dim3(256), 0, stream, scores, attn);
  hipLaunchKernelGGL(k_partial, dim3(256),  dim3(256), 0, stream, wh, attn, partial);
  hipLaunchKernelGGL(k_predict, dim3(32),   dim3(256), 0, stream, hiddens, partial, Wl, bl, out);
}

// Round 2
// 102.514 us; speedup vs baseline: 3.9875x; 3.9875x over previous
//
#include <hip/hip_runtime.h>
#include <stdint.h>
#include <math.h>

#define B_ 32
#define S_ 512
#define H_ 768
#define V_ 30522
#define M_ (B_*S_)   // 16384
#define N1_ 512

typedef __attribute__((ext_vector_type(8))) short bf16x8;
typedef __attribute__((ext_vector_type(4))) float f32x4;

__device__ __forceinline__ float bf2f(unsigned short u){
  union { unsigned int u; float f; } c; c.u = ((unsigned int)u)<<16; return c.f;
}
__device__ __forceinline__ unsigned short f2bf(float f){
  union { float f; unsigned int u; } c; c.f=f;
  unsigned int u = c.u + 0x7FFFu + ((c.u>>16)&1u);
  return (unsigned short)(u>>16);
}
__device__ __forceinline__ bool tbl_get(const void* t, int id, int flag){
  if(flag==1) return ((const int*)t)[id]!=0;
  if(flag==2) return ((const unsigned int*)t)[id]!=0u;   // f32 stored 0.0/1.0
  return ((const unsigned char*)t)[id]!=0;
}
__device__ __forceinline__ void gload_lds16(const void* g, void* l){
  __builtin_amdgcn_global_load_lds(
    (const __attribute__((address_space(1))) void*)g,
    (__attribute__((address_space(3))) void*)l, 16, 0, 0);
}

// ---- K0: detect in_table layout + build per-row mask (0/1 f32) ----
__global__ __launch_bounds__(256) void k_detect_mask(const void* __restrict__ in_table,
  const int* __restrict__ ids, float* __restrict__ maskf){
  __shared__ int sflag;
  if(threadIdx.x==0){
    const int* pi = (const int*)in_table;
    bool all01=true, allf=true;
    for(int i=0;i<64;i++){
      int v = pi[i];
      if(v!=0 && v!=1) all01=false;
      unsigned int u=(unsigned int)v;
      if(u!=0u && u!=0x3F800000u) allf=false;
    }
    sflag = all01 ? 1 : (allf ? 2 : 0);
  }
  __syncthreads();
  const int flag = sflag;
  const int base = blockIdx.x*512;
  for(int i=threadIdx.x; i<512; i+=256){
    const int m = base + i;
    const bool mk = ((m & (S_-1)) != 0) && tbl_get(in_table, ids[m], flag);
    maskf[m] = mk ? 1.f : 0.f;
  }
}

// ---- K1: convert weights to bf16 (pad attention mats 100->128) ----
__global__ __launch_bounds__(256) void k_prepw(
  const float* __restrict__ W1, const float* __restrict__ W2,
  const float* __restrict__ Wa1, const float* __restrict__ Wa2, const float* __restrict__ ba1,
  unsigned short* __restrict__ W1bf, unsigned short* __restrict__ W2bf,
  unsigned short* __restrict__ Wa1bf, float* __restrict__ Wa2p, float* __restrict__ ba1p){
  const int g = blockIdx.x*256 + threadIdx.x, st = gridDim.x*256;
  for(int i=g;i<512*H_;i+=st) W1bf[i]=f2bf(W1[i]);
  for(int i=g;i<H_*512;i+=st) W2bf[i]=f2bf(W2[i]);
  for(int i=g;i<128*H_;i+=st) Wa1bf[i] = (i<100*H_)? f2bf(Wa1[i]) : (unsigned short)0;
  if(g < 128){ Wa2p[g] = (g<100)? Wa2[g] : 0.f; ba1p[g] = (g<100)? ba1[g] : 0.f; }
}

// ---- K2: gather table[ids] -> bf16 A [M,768] ----
__global__ __launch_bounds__(256) void k_gather(const float* __restrict__ table,
  const int* __restrict__ ids, unsigned short* __restrict__ A){
  const int g = blockIdx.x*256 + threadIdx.x, st = gridDim.x*256;
  const int total = M_ * (H_/4);
  for(int c=g; c<total; c+=st){
    const int row = c / (H_/4);
    const int off = (c - row*(H_/4)) << 2;
    const int id = ids[row];
    const float4 v = *(const float4*)(table + (size_t)id*H_ + off);
    ushort4 o; o.x=f2bf(v.x); o.y=f2bf(v.y); o.z=f2bf(v.z); o.w=f2bf(v.w);
    *(ushort4*)(A + (size_t)row*H_ + off) = o;
  }
}

// ---- MFMA GEMM: C[M,NTOT](bf16) = relu(A[M,KTOT](bf16) . Bw[NTOT,KTOT]^T + bias) (* maskf) ----
// 128x128 tile, BK=32, 4 waves (2x2), 4x4 16x16x32 fragments per wave.
// LDS linear for global_load_lds; source slot inverse-swizzled (s ^= (row>>1)&3),
// same swizzle on ds_read -> 2-way banks only.
template<int KTOT, int NTOT, bool DOMASK>
__global__ __launch_bounds__(256) void k_gemm(
  const unsigned short* __restrict__ A, const unsigned short* __restrict__ Bw,
  const float* __restrict__ bias, const float* __restrict__ maskf,
  unsigned short* __restrict__ C)
{
  __shared__ __align__(16) unsigned short As[128*32];
  __shared__ __align__(16) unsigned short Bs[128*32];
  const int tid = threadIdx.x;
  const int lane = tid & 63;
  const int wave = tid >> 6;
  const int wr = wave >> 1, wc = wave & 1;
  const int m0 = blockIdx.x << 7;
  const int n0 = blockIdx.y << 7;

  // staging: chunk f covers (row=f>>2, lds slot=f&3); global slot = (f&3)^((f>>3)&3)
  const int f0 = tid, f1 = 256 + tid;
  const int r0 = f0 >> 2, s0 = ((f0 & 3) ^ ((f0 >> 3) & 3)) << 3;
  const int r1 = f1 >> 2, s1 = ((f1 & 3) ^ ((f1 >> 3) & 3)) << 3;
  const unsigned short* ga0 = A + (size_t)(m0 + r0)*KTOT + s0;
  const unsigned short* ga1 = A + (size_t)(m0 + r1)*KTOT + s1;
  const unsigned short* gb0 = Bw + (size_t)(n0 + r0)*KTOT + s0;
  const unsigned short* gb1 = Bw + (size_t)(n0 + r1)*KTOT + s1;
  unsigned short* la0 = As + (wave<<9);
  unsigned short* la1 = As + 2048 + (wave<<9);
  unsigned short* lb0 = Bs + (wave<<9);
  unsigned short* lb1 = Bs + 2048 + (wave<<9);

  f32x4 acc[4][4] = {};
  const int arow = (wr<<6) + (lane & 15);
  const int brow = (wc<<6) + (lane & 15);
  const int sl   = (((lane>>4) ^ ((lane>>1)&3)) << 3);  // swizzled k-slot (ushorts)

  for(int k0 = 0; k0 < KTOT; k0 += 32){
    gload_lds16(ga0 + k0, la0);
    gload_lds16(ga1 + k0, la1);
    gload_lds16(gb0 + k0, lb0);
    gload_lds16(gb1 + k0, lb1);
    __syncthreads();                       // vmcnt(0) drained by compiler
    bf16x8 a[4], b[4];
    #pragma unroll
    for(int m=0;m<4;m++) a[m] = *(const bf16x8*)(As + (arow + (m<<4))*32 + sl);
    #pragma unroll
    for(int n=0;n<4;n++) b[n] = *(const bf16x8*)(Bs + (brow + (n<<4))*32 + sl);
    #pragma unroll
    for(int m=0;m<4;m++)
      #pragma unroll
      for(int n=0;n<4;n++)
        acc[m][n] = __builtin_amdgcn_mfma_f32_16x16x32_bf16(a[m], b[n], acc[m][n], 0,0,0);
    __syncthreads();                       // all waves done reading tile
  }

  const int crow0 = (lane>>4) << 2;
  const int ccol  = lane & 15;
  float bia[4];
  #pragma unroll
  for(int n=0;n<4;n++) bia[n] = bias[n0 + (wc<<6) + (n<<4) + ccol];
  #pragma unroll
  for(int m=0;m<4;m++){
    const int gr0 = m0 + (wr<<6) + (m<<4) + crow0;
    float mrow[4] = {1.f,1.f,1.f,1.f};
    if(DOMASK){
      const float4 mk4 = *(const float4*)(maskf + gr0);
      mrow[0]=mk4.x; mrow[1]=mk4.y; mrow[2]=mk4.z; mrow[3]=mk4.w;
    }
    #pragma unroll
    for(int j=0;j<4;j++){
      const size_t rbase = (size_t)(gr0 + j) * NTOT;
      #pragma unroll
      for(int n=0;n<4;n++){
        float v = acc[m][n][j] + bia[n];
        v = fmaxf(v, 0.f);
        if(DOMASK) v *= mrow[j];
        C[rbase + n0 + (wc<<6) + (n<<4) + ccol] = f2bf(v);
      }
    }
  }
}

// ---- K5: scores[m] = Wa2 . tanh(wh[m] @ Wa1^T + ba1) + ba2 via MFMA (N padded to 128) ----
__global__ __launch_bounds__(256) void k_score(
  const unsigned short* __restrict__ A, const unsigned short* __restrict__ Bw,
  const float* __restrict__ ba1p, const float* __restrict__ Wa2p, const float* __restrict__ ba2,
  float* __restrict__ scores)
{
  __shared__ __align__(16) unsigned short As[128*32];
  __shared__ __align__(16) unsigned short Bs[128*32];
  __shared__ float sums[128][2];
  const int tid = threadIdx.x;
  const int lane = tid & 63;
  const int wave = tid >> 6;
  const int wr = wave >> 1, wc = wave & 1;
  const int m0 = blockIdx.x << 7;

  const int f0 = tid, f1 = 256 + tid;
  const int r0 = f0 >> 2, s0 = ((f0 & 3) ^ ((f0 >> 3) & 3)) << 3;
  const int r1 = f1 >> 2, s1 = ((f1 & 3) ^ ((f1 >> 3) & 3)) << 3;
  const unsigned short* ga0 = A + (size_t)(m0 + r0)*H_ + s0;
  const unsigned short* ga1 = A + (size_t)(m0 + r1)*H_ + s1;
  const unsigned short* gb0 = Bw + (size_t)r0*H_ + s0;
  const unsigned short* gb1 = Bw + (size_t)r1*H_ + s1;
  unsigned short* la0 = As + (wave<<9);
  unsigned short* la1 = As + 2048 + (wave<<9);
  unsigned short* lb0 = Bs + (wave<<9);
  unsigned short* lb1 = Bs + 2048 + (wave<<9);

  f32x4 acc[4][4] = {};
  const int arow = (wr<<6) + (lane & 15);
  const int brow = (wc<<6) + (lane & 15);
  const int sl   = (((lane>>4) ^ ((lane>>1)&3)) << 3);

  for(int k0 = 0; k0 < H_; k0 += 32){
    gload_lds16(ga0 + k0, la0);
    gload_lds16(ga1 + k0, la1);
    gload_lds16(gb0 + k0, lb0);
    gload_lds16(gb1 + k0, lb1);
    __syncthreads();
    bf16x8 a[4], b[4];
    #pragma unroll
    for(int m=0;m<4;m++) a[m] = *(const bf16x8*)(As + (arow + (m<<4))*32 + sl);
    #pragma unroll
    for(int n=0;n<4;n++) b[n] = *(const bf16x8*)(Bs + (brow + (n<<4))*32 + sl);
    #pragma unroll
    for(int m=0;m<4;m++)
      #pragma unroll
      for(int n=0;n<4;n++)
        acc[m][n] = __builtin_amdgcn_mfma_f32_16x16x32_bf16(a[m], b[n], acc[m][n], 0,0,0);
    __syncthreads();
  }

  float psum[4][4] = {};
  #pragma unroll
  for(int n=0;n<4;n++){
    const int c = (wc<<6) + (n<<4) + (lane & 15);
    const float w2 = Wa2p[c], bb = ba1p[c];
    #pragma unroll
    for(int m=0;m<4;m++)
      #pragma unroll
      for(int j=0;j<4;j++)
        psum[m][j] = fmaf(tanhf(acc[m][n][j] + bb), w2, psum[m][j]);
  }
  #pragma unroll
  for(int msk=1; msk<16; msk<<=1)
    #pragma unroll
    for(int m=0;m<4;m++)
      #pragma unroll
      for(int j=0;j<4;j++)
        psum[m][j] += __shfl_xor(psum[m][j], msk, 64);
  if((lane & 15) == 0){
    #pragma unroll
    for(int m=0;m<4;m++)
      #pragma unroll
      for(int j=0;j<4;j++)
        sums[(wr<<6) + (m<<4) + ((lane>>4)<<2) + j][wc] = psum[m][j];
  }
  __syncthreads();
  if(tid < 128) scores[m0 + tid] = sums[tid][0] + sums[tid][1] + ba2[0];
}

// ---- K6: per-batch softmax over s=1..511 ----
__global__ __launch_bounds__(256) void k_softmax(const float* __restrict__ scores, float* __restrict__ attn){
  __shared__ float red[256];
  const int b = blockIdx.x, tid = threadIdx.x;
  const float s1 = (tid==0) ? -1e30f : scores[b*S_ + tid];
  const float s2 = scores[b*S_ + tid + 256];
  red[tid] = fmaxf(s1, s2); __syncthreads();
  for(int st=128; st>0; st>>=1){ if(tid<st) red[tid]=fmaxf(red[tid], red[tid+st]); __syncthreads(); }
  const float mx = red[0]; __syncthreads();
  const float e1 = (tid==0) ? 0.f : __expf(s1-mx);
  const float e2 = __expf(s2-mx);
  red[tid] = e1+e2; __syncthreads();
  for(int st=128; st>0; st>>=1){ if(tid<st) red[tid]+=red[tid+st]; __syncthreads(); }
  const float inv = 1.f/red[0];
  attn[b*S_+tid] = e1*inv;
  attn[b*S_+tid+256] = e2*inv;
}

// ---- K7: partial[b][ch][h] = sum_{s in 64-chunk} attn[s]*wh[b,s,h] ----
__global__ __launch_bounds__(256) void k_partial(const unsigned short* __restrict__ wh,
  const float* __restrict__ attn, float* __restrict__ partial){
  const int b = blockIdx.x >> 3, ch = blockIdx.x & 7, tid = threadIdx.x;
  __shared__ float wts[64];
  if(tid < 64) wts[tid] = attn[b*S_ + (ch<<6) + tid];
  __syncthreads();
  float a0=0.f, a1=0.f, a2=0.f;
  for(int t=0;t<64;t++){
    const float wv = wts[t];
    const size_t base = ((size_t)(b*S_ + (ch<<6) + t))*H_;
    a0 = fmaf(wv, bf2f(wh[base + tid      ]), a0);
    a1 = fmaf(wv, bf2f(wh[base + tid + 256]), a1);
    a2 = fmaf(wv, bf2f(wh[base + tid + 512]), a2);
  }
  float* pp = partial + ((size_t)((b<<3)+ch))*H_;
  pp[tid] = a0; pp[tid+256] = a1; pp[tid+512] = a2;
}

// ---- K8: predicts[b] = [hiddens[b,0,:], cls_k[b,:]] @ Wl^T + bl ----
__global__ __launch_bounds__(256) void k_predict(const float* __restrict__ hiddens,
  const float* __restrict__ partial, const float* __restrict__ Wl, const float* __restrict__ bl,
  float* __restrict__ out){
  __shared__ float ck[768];
  __shared__ float red[256];
  const int b = blockIdx.x, tid = threadIdx.x;
  #pragma unroll
  for(int r=0;r<3;r++){
    const int h = tid + (r<<8);
    float s=0.f;
    for(int c=0;c<8;c++) s += partial[((size_t)((b<<3)+c))*H_ + h];
    ck[h]=s;
  }
  __syncthreads();
  const float* hid = hiddens + (size_t)b * S_ * H_;
  for(int c=0;c<3;c++){
    float p=0.f;
    #pragma unroll
    for(int r=0;r<3;r++){
      const int h = tid + (r<<8);
      p = fmaf(hid[h], Wl[c*1536 + h], p);
      p = fmaf(ck[h],  Wl[c*1536 + 768 + h], p);
    }
    red[tid]=p; __syncthreads();
    for(int st=128; st>0; st>>=1){ if(tid<st) red[tid]+=red[tid+st]; __syncthreads(); }
    if(tid==0) out[b*3+c] = red[0] + bl[c];
    __syncthreads();
  }
}

extern "C" void kernel_launch(void* const* d_in, const int* in_sizes, int n_in,
                              void* d_out, int out_size, void* d_ws, size_t ws_size,
                              hipStream_t stream)
{
  const float* hiddens = (const float*)d_in[0];
  const int*   ids     = (const int*)d_in[1];
  const void*  in_tab  = d_in[2];
  const float* table   = (const float*)d_in[3];
  const float* W1      = (const float*)d_in[4];
  const float* b1      = (const float*)d_in[5];
  const float* W2      = (const float*)d_in[6];
  const float* b2      = (const float*)d_in[7];
  const float* Wa1     = (const float*)d_in[8];
  const float* ba1     = (const float*)d_in[9];
  const float* Wa2     = (const float*)d_in[10];
  const float* ba2     = (const float*)d_in[11];
  const float* Wl      = (const float*)d_in[12];
  const float* bl      = (const float*)d_in[13];
  float* out = (float*)d_out;

  char* w = (char*)d_ws;
  unsigned short* Abf   = (unsigned short*)w;                         // 25165824 B (aliased by wh)
  unsigned short* wh    = Abf;                                        // alias: A dead after mlp1
  unsigned short* x     = (unsigned short*)(w + 25165824);            // 16777216
  unsigned short* W1bf  = (unsigned short*)(w + 41943040);            // 786432
  unsigned short* W2bf  = (unsigned short*)(w + 42729472);            // 786432
  unsigned short* Wa1bf = (unsigned short*)(w + 43515904);            // 196608
  float* Wa2p    = (float*)(w + 43712512);                            // 512
  float* ba1p    = (float*)(w + 43713024);                            // 512
  float* maskf   = (float*)(w + 43713536);                            // 65536
  float* scores  = (float*)(w + 43779072);                            // 65536
  float* attn    = (float*)(w + 43844608);                            // 65536
  float* partial = (float*)(w + 43910144);                            // 786432

  hipLaunchKernelGGL(k_detect_mask, dim3(32),  dim3(256), 0, stream, in_tab, ids, maskf);
  hipLaunchKernelGGL(k_prepw,  dim3(768),  dim3(256), 0, stream, W1, W2, Wa1, Wa2, ba1, W1bf, W2bf, Wa1bf, Wa2p, ba1p);
  hipLaunchKernelGGL(k_gather, dim3(3072), dim3(256), 0, stream, table, ids, Abf);
  hipLaunchKernelGGL((k_gemm<H_, N1_, false>), dim3(128, 4), dim3(256), 0, stream, Abf, W1bf, b1, (const float*)nullptr, x);
  hipLaunchKernelGGL((k_gemm<N1_, H_, true>),  dim3(128, 6), dim3(256), 0, stream, x, W2bf, b2, maskf, wh);
  hipLaunchKernelGGL(k_score,   dim3(128), dim3(256), 0, stream, wh, Wa1bf, ba1p, Wa2p, ba2, scores);
  hipLaunchKernelGGL(k_softmax, dim3(32),  dim3(256), 0, stream, scores, attn);
  hipLaunchKernelGGL(k_partial, dim3(256), dim3(256), 0, stream, wh, attn, partial);
  hipLaunchKernelGGL(k_predict, dim3(32),  dim3(256), 0, stream, hiddens, partial, Wl, bl, out);
}